// Round 4
// baseline (239.017 us; speedup 1.0000x reference)
//
#include <hip/hip_runtime.h>
#include <cfloat>

#define C_DIM 256
#define HW    4096
#define NE    1024
#define NPIX  65536
#define TAU   0.15f
#define ZSTR  264   // fp16 per Z-LDS pixel row: 256 ch + 8 pad (528 B, 16B-aligned)

typedef __attribute__((ext_vector_type(8))) _Float16 half8_t;
typedef __attribute__((ext_vector_type(4))) float floatx4;

// monotone float -> uint32 (for packed (d,idx) u64 min with lowest-index tie-break)
__device__ __forceinline__ unsigned int fenc(float f) {
  unsigned int u = __float_as_uint(f);
  return (u & 0x80000000u) ? ~u : (u | 0x80000000u);
}

// ---------------- ws layout (1.05 MB total) ----------------
// @0       float acc (loss)            [zeroed per launch]
// @8       int   ccount                [zeroed per launch]
// @4096    float e2[1024]
// @8192    _Float16 EhfP[1024*256]     (512 KiB fp16 codebook, MFMA-fragment-packed)
// @532480  int   idx[65536]            (256 KiB)
// @794624  int   clist[65536]          (256 KiB, ends 1056768)

// K0 (fused): blocks [0,128) pack codebook into MFMA A-fragment order;
// blocks [128,384) compute ||e||^2 per codeword (one wave per codeword).
__global__ __launch_bounds__(256)
void prep_kernel(const float* __restrict__ cb, _Float16* __restrict__ EhfP,
                 float* __restrict__ e2) {
  if (blockIdx.x < 128) {
    const int g = blockIdx.x >> 3, it = blockIdx.x & 7;
    const int sidx = it * 256 + (int)threadIdx.x;       // (ks*256 + i*64 + lane)
    const int ks = sidx >> 8, i = (sidx >> 6) & 3, lane = sidx & 63;
    const int ln = lane & 15, quad = lane >> 4;
    const float* src = cb + (size_t)(g * 64 + i * 16 + ln) * C_DIM + ks * 32 + quad * 8;
    const float4 v0 = *(const float4*)(src);
    const float4 v1 = *(const float4*)(src + 4);
    half8_t h;
    h[0] = (_Float16)v0.x; h[1] = (_Float16)v0.y; h[2] = (_Float16)v0.z; h[3] = (_Float16)v0.w;
    h[4] = (_Float16)v1.x; h[5] = (_Float16)v1.y; h[6] = (_Float16)v1.z; h[7] = (_Float16)v1.w;
    *(half8_t*)(EhfP + (size_t)g * 16384 + (size_t)sidx * 8) = h;
  } else {
    const int bid = blockIdx.x - 128;
    const int wave = (bid * 256 + (int)threadIdx.x) >> 6;
    const int lane = threadIdx.x & 63;
    const float4 v = *(const float4*)(cb + (size_t)wave * C_DIM + lane * 4);
    float s = v.x * v.x + v.y * v.y + v.z * v.z + v.w * v.w;
    #pragma unroll
    for (int off = 32; off; off >>= 1) s += __shfl_down(s, off, 64);
    if (lane == 0) e2[wave] = s;
  }
}

// K1: fp16 MFMA screen. Tile 64 px: LDS 37.9 KB -> 4 blocks/CU (4 waves/SIMD,
// was 2) for latency hiding. Wave (wc,wp) owns 64 cw x 32 px = 4x2 grid of
// 16x16x32 MFMAs. A (global/L2) and B (LDS) double-buffered depth-1; with
// 4 waves/SIMD the round-robin gives ~600 cy load-to-use, covering L2.
__global__ __launch_bounds__(256, 4)
void screen_kernel(const float* __restrict__ z, const _Float16* __restrict__ EhfP,
                   const float* __restrict__ e2, int* __restrict__ idx_out,
                   int* __restrict__ clist, int* __restrict__ ccount) {
  __shared__ __align__(16) _Float16 Zl[64 * ZSTR];    // 33792 B
  __shared__ float e2l[NE];                           // 4096 B

  const int tid = threadIdx.x;
  const int ptile = blockIdx.x * 64;
  const int b = ptile >> 12, pb = ptile & 4095;
  const float* zb = z + (size_t)b * (C_DIM * HW) + pb;

  // stage Z: z[k][p] fp32 -> Zl[p][k] fp16. Each thread: 8 coalesced scalar loads
  // (one pixel, 8 contiguous channels) -> one ds_write_b128.
  #pragma unroll
  for (int it = 0; it < 8; ++it) {
    const int flat = it * 256 + tid;
    const int p = flat & 63, kb = flat >> 6;
    float f[8];
    #pragma unroll
    for (int j = 0; j < 8; ++j) f[j] = zb[(size_t)(kb * 8 + j) * HW + p];
    half8_t h;
    #pragma unroll
    for (int j = 0; j < 8; ++j) h[j] = (_Float16)f[j];
    *(half8_t*)&Zl[p * ZSTR + kb * 8] = h;
  }
  #pragma unroll
  for (int i = 0; i < 4; ++i) e2l[i * 256 + tid] = e2[i * 256 + tid];
  __syncthreads();

  const int lane = tid & 63;
  const int w = tid >> 6;
  const int wc = w & 1, wp = w >> 1;
  const int ln = lane & 15, quad = lane >> 4;

  // A stream: wave wc's fragments for chunk nc at EhfP + (nc*2+wc)*16384 halves;
  // step (nc,ks), frag i: + ks*2048 + i*512 + lane*8 halves (16B/lane, coalesced).
  const _Float16* aBase = EhfP + (size_t)wc * 16384 + (size_t)lane * 8;
  const char* rowB[2];
  #pragma unroll
  for (int j = 0; j < 2; ++j)
    rowB[j] = (const char*)(&Zl[(wp * 32 + j * 16 + ln) * ZSTR + quad * 8]);

  float d1[2], d2[2]; int i1[2];
  #pragma unroll
  for (int j = 0; j < 2; ++j) { d1[j] = FLT_MAX; d2[j] = FLT_MAX; i1[j] = 0; }

  half8_t abuf[2][4], bbuf[2][2];
  // prologue: fragments for step 0
  #pragma unroll
  for (int i = 0; i < 4; ++i) abuf[0][i] = *(const half8_t*)(aBase + i * 512);
  #pragma unroll
  for (int j = 0; j < 2; ++j) bbuf[0][j] = *(const half8_t*)(rowB[j]);

  for (int nc = 0; nc < 8; ++nc) {
    floatx4 acc[4][2];
    #pragma unroll
    for (int i = 0; i < 4; ++i)
      #pragma unroll
      for (int j = 0; j < 2; ++j) acc[i][j] = (floatx4){0.f, 0.f, 0.f, 0.f};

    #pragma unroll
    for (int ks = 0; ks < 8; ++ks) {
      const int s = nc * 8 + ks;
      const int cur = ks & 1, nxt = cur ^ 1;
      // prefetch step s+1 (clamped to last step: redundant reload, in-bounds)
      const int sp = s + 1 > 63 ? 63 : s + 1;
      const size_t aoff = (size_t)(sp >> 3) * 32768 + (size_t)(sp & 7) * 2048;
      #pragma unroll
      for (int i = 0; i < 4; ++i) abuf[nxt][i] = *(const half8_t*)(aBase + aoff + i * 512);
      const int bks = sp & 7;
      #pragma unroll
      for (int j = 0; j < 2; ++j) bbuf[nxt][j] = *(const half8_t*)(rowB[j] + bks * 64);
      // compute on current buffers
      #pragma unroll
      for (int i = 0; i < 4; ++i)
        #pragma unroll
        for (int j = 0; j < 2; ++j)
          acc[i][j] = __builtin_amdgcn_mfma_f32_16x16x32_f16(abuf[cur][i], bbuf[cur][j], acc[i][j], 0, 0, 0);
    }

    // epilogue: d' = e2 - 2*dot; per-lane (d1,i1,d2). cw index ascending -> '<' keeps first.
    const int cwb = nc * 128 + wc * 64;
    #pragma unroll
    for (int i = 0; i < 4; ++i) {
      const int cw0 = cwb + i * 16 + quad * 4;    // C/D: row = quad*4 + r (codeword)
      float ee[4];
      #pragma unroll
      for (int r = 0; r < 4; ++r) ee[r] = e2l[cw0 + r];
      #pragma unroll
      for (int j = 0; j < 2; ++j) {
        #pragma unroll
        for (int r = 0; r < 4; ++r) {
          const float d = fmaf(-2.0f, acc[i][j][r], ee[r]);
          const bool lt = d < d1[j];
          const float hi = lt ? d1[j] : d;
          d1[j] = lt ? d : d1[j];
          i1[j] = lt ? (cw0 + r) : i1[j];
          d2[j] = fminf(d2[j], hi);
        }
      }
    }
  }

  // cross-quad butterfly (lanes l, l^16, l^32 share pixel col = lane&15)
  #pragma unroll
  for (int j = 0; j < 2; ++j) {
    #pragma unroll
    for (int m = 16; m <= 32; m <<= 1) {
      const float od1 = __shfl_xor(d1[j], m, 64);
      const int   oi1 = __shfl_xor(i1[j], m, 64);
      const float od2 = __shfl_xor(d2[j], m, 64);
      const bool take = (od1 < d1[j]) || (od1 == d1[j] && oi1 < i1[j]);
      const float hi = take ? d1[j] : od1;
      d1[j] = take ? od1 : d1[j];
      i1[j] = take ? oi1 : i1[j];
      d2[j] = fminf(fminf(d2[j], od2), hi);
    }
  }

  // cross-wave (wc) merge via LDS (reuse Zl)
  __syncthreads();
  float* rd1 = (float*)Zl;
  int*   ri1 = (int*)Zl + 128;
  float* rd2 = (float*)Zl + 256;
  if (lane < 16) {
    #pragma unroll
    for (int j = 0; j < 2; ++j) {
      const int p = wp * 32 + j * 16 + ln;
      rd1[wc * 64 + p] = d1[j];
      ri1[wc * 64 + p] = i1[j];
      rd2[wc * 64 + p] = d2[j];
    }
  }
  __syncthreads();
  if (tid < 64) {
    const float a1 = rd1[tid], b1 = rd1[64 + tid];
    const int   ai = ri1[tid], bi = ri1[64 + tid];
    const float a2 = rd2[tid], b2 = rd2[64 + tid];
    const bool take = (b1 < a1) || (b1 == a1 && bi < ai);
    const float d1f = take ? b1 : a1;
    const int   i1f = take ? bi : ai;
    const float hi  = take ? a1 : b1;
    const float d2f = fminf(fminf(a2, b2), hi);
    const int gp = ptile + tid;
    idx_out[gp] = i1f;
    if ((d2f - d1f) <= TAU) {   // fp16 gap error sigma ~3e-2; TAU = 5 sigma
      const int pos = atomicAdd(ccount, 1);
      clist[pos] = gp;
    }
  }
}

// K2: exact fp32 rescan. One block per group of 4 contested pixels, all 1024
// codewords in-block. fma chain per (cw,px) bit-identical to prior passing version.
__global__ __launch_bounds__(256)
void rescan_kernel(const float* __restrict__ z, const float* __restrict__ cb,
                   const float* __restrict__ e2, const int* __restrict__ clist,
                   const int* __restrict__ ccount, int* __restrict__ idx_out) {
  __shared__ __align__(16) float zl[4][C_DIM];    // [px][k] -> float4 broadcast reads
  __shared__ int pxs[4];
  __shared__ unsigned long long bestk[4];
  const int n = *ccount;
  const int ngroups = (n + 3) >> 2;
  for (int g = blockIdx.x; g < ngroups; g += gridDim.x) {
    const int base = g * 4;
    if ((int)threadIdx.x < 4) {
      pxs[threadIdx.x] = clist[min(base + (int)threadIdx.x, n - 1)];  // pad w/ dup (idempotent)
      bestk[threadIdx.x] = ~0ULL;
    }
    __syncthreads();
    {
      const int k = threadIdx.x;
      #pragma unroll
      for (int i = 0; i < 4; ++i) {
        const int gp = pxs[i];
        zl[i][k] = z[(size_t)(gp >> 12) * (C_DIM * HW) + (size_t)k * HW + (gp & 4095)];
      }
    }
    __syncthreads();
    unsigned long long mykey[4] = {~0ULL, ~0ULL, ~0ULL, ~0ULL};
    #pragma unroll 1
    for (int o = 0; o < 4; ++o) {
      const int cw = o * 256 + (int)threadIdx.x;
      const float* row = cb + (size_t)cw * C_DIM;
      float dot[4] = {0.f, 0.f, 0.f, 0.f};
      #pragma unroll 4
      for (int k0 = 0; k0 < C_DIM; k0 += 4) {
        const float4 ev = *(const float4*)(row + k0);   // coalesced-by-row, L2-hot
        #pragma unroll
        for (int i = 0; i < 4; ++i) {
          const float4 zz = *(const float4*)&zl[i][k0]; // uniform addr -> LDS broadcast
          dot[i] = fmaf(ev.x, zz.x, dot[i]);
          dot[i] = fmaf(ev.y, zz.y, dot[i]);
          dot[i] = fmaf(ev.z, zz.z, dot[i]);
          dot[i] = fmaf(ev.w, zz.w, dot[i]);
        }
      }
      const float ee = e2[cw];
      #pragma unroll
      for (int i = 0; i < 4; ++i) {
        const float d = fmaf(-2.0f, dot[i], ee);
        const unsigned long long key = ((unsigned long long)fenc(d) << 32) | (unsigned)cw;
        mykey[i] = key < mykey[i] ? key : mykey[i];
      }
    }
    // wave-level u64 min reduce, then 1 shared atomic per wave per pixel
    #pragma unroll
    for (int i = 0; i < 4; ++i) {
      unsigned long long k = mykey[i];
      #pragma unroll
      for (int off = 32; off; off >>= 1) {
        const unsigned long long ok = __shfl_xor(k, off, 64);
        k = ok < k ? ok : k;
      }
      if ((threadIdx.x & 63) == 0) atomicMin(&bestk[i], k);
    }
    __syncthreads();
    if ((int)threadIdx.x < 4)
      idx_out[pxs[threadIdx.x]] = (int)(unsigned)(bestk[threadIdx.x] & 0xFFFFFFFFull);
    __syncthreads();
  }
}

// K3: gather zq (NCHW) + loss sum. 64 px x 4 channel-segments per block: 4x the
// blocks (1024) -> 4x occupancy to hide strided-z / gathered-e latencies. z/out
// accesses stay wave-coalesced (each wave = one channel segment, 64 consecutive px).
__global__ __launch_bounds__(256)
void gather_loss_kernel(const float* __restrict__ z, const float* __restrict__ cb,
                        const int* __restrict__ idx,
                        float* __restrict__ out, float* __restrict__ acc) {
  const int tid = threadIdx.x;
  const int px = blockIdx.x * 64 + (tid & 63);
  const int cbase = (tid >> 6) * 64;
  const int id = idx[px];
  const int b = px >> 12, p = px & 4095;
  const float* zrow = z   + (size_t)b * (C_DIM * HW) + p;
  float*       orow = out + (size_t)b * (C_DIM * HW) + p;
  const float* erow = cb + (size_t)id * C_DIM;
  float s = 0.f;
  for (int c0 = cbase; c0 < cbase + 64; c0 += 4) {
    const float4 ev = *(const float4*)(erow + c0);
    const float e[4] = {ev.x, ev.y, ev.z, ev.w};
    #pragma unroll
    for (int j = 0; j < 4; ++j) {
      const float zv = zrow[(size_t)(c0 + j) * HW];
      const float dd = e[j] - zv;
      s = fmaf(dd, dd, s);
      orow[(size_t)(c0 + j) * HW] = e[j];
    }
  }
  __shared__ float sdata[256];
  sdata[tid] = s;
  __syncthreads();
  #pragma unroll
  for (int off = 128; off; off >>= 1) {
    if (tid < off) sdata[tid] += sdata[tid + off];
    __syncthreads();
  }
  if (tid == 0) atomicAdd(acc, sdata[0]);
}

__global__ void finalize_kernel(const float* __restrict__ acc, float* __restrict__ loss_out) {
  *loss_out = 1.25f * (*acc) * (1.0f / 16777216.0f);
}

extern "C" void kernel_launch(void* const* d_in, const int* in_sizes, int n_in,
                              void* d_out, int out_size, void* d_ws, size_t ws_size,
                              hipStream_t stream) {
  const float* z  = (const float*)d_in[0];
  const float* cb = (const float*)d_in[1];
  float* out = (float*)d_out;
  char* ws = (char*)d_ws;

  float*    acc    = (float*)ws;
  int*      ccount = (int*)(ws + 8);
  float*    e2     = (float*)(ws + 4096);
  _Float16* EhfP   = (_Float16*)(ws + 8192);
  int*      idx    = (int*)(ws + 532480);
  int*      clist  = (int*)(ws + 794624);

  (void)hipMemsetAsync(d_ws, 0, 16, stream);
  prep_kernel<<<384, 256, 0, stream>>>(cb, EhfP, e2);
  screen_kernel<<<NPIX / 64, 256, 0, stream>>>(z, EhfP, e2, idx, clist, ccount);
  rescan_kernel<<<1024, 256, 0, stream>>>(z, cb, e2, clist, ccount, idx);
  gather_loss_kernel<<<NPIX / 64, 256, 0, stream>>>(z, cb, idx, out, acc);
  finalize_kernel<<<1, 1, 0, stream>>>(acc, out + 16777216);
}

// Round 5
// 222.608 us; speedup vs baseline: 1.0737x; 1.0737x over previous
//
#include <hip/hip_runtime.h>
#include <cfloat>

#define C_DIM 256
#define HW    4096
#define NE    1024
#define NPIX  65536
#define TAU   0.15f
#define ZSTR  264   // fp16 per Z-LDS pixel row: 256 ch + 8 pad (528 B, 16B-aligned)

typedef __attribute__((ext_vector_type(8))) _Float16 half8_t;
typedef __attribute__((ext_vector_type(4))) float floatx4;

// monotone float -> uint32 (for packed (d,idx) u64 min with lowest-index tie-break)
__device__ __forceinline__ unsigned int fenc(float f) {
  unsigned int u = __float_as_uint(f);
  return (u & 0x80000000u) ? ~u : (u | 0x80000000u);
}

// ---------------- ws layout (1.05 MB total) ----------------
// @0       float acc (Σ d1 + Σ z², loss numerator)  [zeroed per launch]
// @8       int   ccount                             [zeroed per launch]
// @4096    float e2[1024]
// @8192    _Float16 EhfP[1024*256]     (512 KiB fp16 codebook, MFMA-fragment-packed)
// @532480  int   idx[65536]            (256 KiB)
// @794624  int   clist[65536]          (256 KiB, ends 1056768)

// K0 (fused): blocks [0,128) pack codebook into MFMA A-fragment order;
// blocks [128,384) compute ||e||^2 per codeword (one wave per codeword).
__global__ __launch_bounds__(256)
void prep_kernel(const float* __restrict__ cb, _Float16* __restrict__ EhfP,
                 float* __restrict__ e2) {
  if (blockIdx.x < 128) {
    const int g = blockIdx.x >> 3, it = blockIdx.x & 7;
    const int sidx = it * 256 + (int)threadIdx.x;       // (ks*256 + i*64 + lane)
    const int ks = sidx >> 8, i = (sidx >> 6) & 3, lane = sidx & 63;
    const int ln = lane & 15, quad = lane >> 4;
    const float* src = cb + (size_t)(g * 64 + i * 16 + ln) * C_DIM + ks * 32 + quad * 8;
    const float4 v0 = *(const float4*)(src);
    const float4 v1 = *(const float4*)(src + 4);
    half8_t h;
    h[0] = (_Float16)v0.x; h[1] = (_Float16)v0.y; h[2] = (_Float16)v0.z; h[3] = (_Float16)v0.w;
    h[4] = (_Float16)v1.x; h[5] = (_Float16)v1.y; h[6] = (_Float16)v1.z; h[7] = (_Float16)v1.w;
    *(half8_t*)(EhfP + (size_t)g * 16384 + (size_t)sidx * 8) = h;
  } else {
    const int bid = blockIdx.x - 128;
    const int wave = (bid * 256 + (int)threadIdx.x) >> 6;
    const int lane = threadIdx.x & 63;
    const float4 v = *(const float4*)(cb + (size_t)wave * C_DIM + lane * 4);
    float s = v.x * v.x + v.y * v.y + v.z * v.z + v.w * v.w;
    #pragma unroll
    for (int off = 32; off; off >>= 1) s += __shfl_down(s, off, 64);
    if (lane == 0) e2[wave] = s;
  }
}

// K1: fp16 MFMA screen — REVERTED to the proven 128-px/j=4 structure (round-4's
// 64-px/4-blocks experiment regressed: A-traffic doubled, MfmaUtil fell; the
// kernel is A-reuse-bound, not occupancy-bound). NEW: fused loss accumulation —
// Σz² (exact fp32, during staging) + Σd1 (from the merge) -> atomicAdd(acc).
// loss = 1.25*(Σd1+Σz²)/16.8M; fp16-dot errors are zero-mean, Σ error ~6e-7.
__global__ __launch_bounds__(256, 2)
void screen_kernel(const float* __restrict__ z, const _Float16* __restrict__ EhfP,
                   const float* __restrict__ e2, int* __restrict__ idx_out,
                   int* __restrict__ clist, int* __restrict__ ccount,
                   float* __restrict__ acc_out) {
  __shared__ __align__(16) _Float16 Zl[128 * ZSTR];   // 67584 B
  __shared__ float e2l[NE];                           // 4096 B

  const int tid = threadIdx.x;
  const int ptile = blockIdx.x * 128;
  const int b = ptile >> 12, pb = ptile & 4095;
  const float* zb = z + (size_t)b * (C_DIM * HW) + pb;

  // stage Z: z[k][p] fp32 -> Zl[p][k] fp16; accumulate Σz² in fp32 on the side.
  float s_z2 = 0.f;
  #pragma unroll
  for (int it = 0; it < 16; ++it) {
    const int flat = it * 256 + tid;
    const int p = flat & 127, kb = flat >> 7;
    float f[8];
    #pragma unroll
    for (int j = 0; j < 8; ++j) f[j] = zb[(size_t)(kb * 8 + j) * HW + p];
    half8_t h;
    #pragma unroll
    for (int j = 0; j < 8; ++j) { s_z2 = fmaf(f[j], f[j], s_z2); h[j] = (_Float16)f[j]; }
    *(half8_t*)&Zl[p * ZSTR + kb * 8] = h;
  }
  #pragma unroll
  for (int i = 0; i < 4; ++i) e2l[i * 256 + tid] = e2[i * 256 + tid];
  __syncthreads();

  const int lane = tid & 63;
  const int w = tid >> 6;
  const int wc = w & 1, wp = w >> 1;
  const int ln = lane & 15, quad = lane >> 4;

  // A stream: wave wc's fragments for chunk nc at EhfP + (nc*2+wc)*16384 halves;
  // step (nc,ks), frag i: + ks*2048 + i*512 + lane*8 halves (16B/lane, coalesced).
  const _Float16* aBase = EhfP + (size_t)wc * 16384 + (size_t)lane * 8;
  const char* rowB[4];
  #pragma unroll
  for (int j = 0; j < 4; ++j)
    rowB[j] = (const char*)(&Zl[(wp * 64 + j * 16 + ln) * ZSTR + quad * 8]);

  float d1[4], d2[4]; int i1[4];
  #pragma unroll
  for (int j = 0; j < 4; ++j) { d1[j] = FLT_MAX; d2[j] = FLT_MAX; i1[j] = 0; }

  half8_t abuf[2][4], bbuf[2][4];
  // prologue: fragments for step 0 (nc=0, ks=0)
  #pragma unroll
  for (int i = 0; i < 4; ++i) abuf[0][i] = *(const half8_t*)(aBase + i * 512);
  #pragma unroll
  for (int j = 0; j < 4; ++j) bbuf[0][j] = *(const half8_t*)(rowB[j]);

  for (int nc = 0; nc < 8; ++nc) {
    floatx4 acc[4][4];
    #pragma unroll
    for (int i = 0; i < 4; ++i)
      #pragma unroll
      for (int j = 0; j < 4; ++j) acc[i][j] = (floatx4){0.f, 0.f, 0.f, 0.f};

    #pragma unroll
    for (int ks = 0; ks < 8; ++ks) {
      const int cur = ks & 1, nxt = cur ^ 1;
      // prefetch step s+1 (clamped to last step: redundant reload, in-bounds)
      const int s1 = nc * 8 + ks + 1;
      const int sp = s1 > 63 ? 63 : s1;
      const size_t aoff = (size_t)(sp >> 3) * 32768 + (size_t)(sp & 7) * 2048;
      const int bks = sp & 7;
      #pragma unroll
      for (int i = 0; i < 4; ++i) abuf[nxt][i] = *(const half8_t*)(aBase + aoff + i * 512);
      #pragma unroll
      for (int j = 0; j < 4; ++j) bbuf[nxt][j] = *(const half8_t*)(rowB[j] + bks * 64);
      // compute on current buffers
      #pragma unroll
      for (int i = 0; i < 4; ++i)
        #pragma unroll
        for (int j = 0; j < 4; ++j)
          acc[i][j] = __builtin_amdgcn_mfma_f32_16x16x32_f16(abuf[cur][i], bbuf[cur][j], acc[i][j], 0, 0, 0);
    }

    // epilogue: d' = e2 - 2*dot; per-lane (d1,i1,d2). cw index ascending -> '<' keeps first.
    const int cwb = nc * 128 + wc * 64;
    #pragma unroll
    for (int i = 0; i < 4; ++i) {
      const int cw0 = cwb + i * 16 + quad * 4;    // C/D: row = quad*4 + r (codeword)
      float ee[4];
      #pragma unroll
      for (int r = 0; r < 4; ++r) ee[r] = e2l[cw0 + r];
      #pragma unroll
      for (int j = 0; j < 4; ++j) {
        #pragma unroll
        for (int r = 0; r < 4; ++r) {
          const float d = fmaf(-2.0f, acc[i][j][r], ee[r]);
          const bool lt = d < d1[j];
          const float hi = lt ? d1[j] : d;
          d1[j] = lt ? d : d1[j];
          i1[j] = lt ? (cw0 + r) : i1[j];
          d2[j] = fminf(d2[j], hi);
        }
      }
    }
  }

  // cross-quad butterfly (lanes l, l^16, l^32 share pixel col = lane&15)
  #pragma unroll
  for (int j = 0; j < 4; ++j) {
    #pragma unroll
    for (int m = 16; m <= 32; m <<= 1) {
      const float od1 = __shfl_xor(d1[j], m, 64);
      const int   oi1 = __shfl_xor(i1[j], m, 64);
      const float od2 = __shfl_xor(d2[j], m, 64);
      const bool take = (od1 < d1[j]) || (od1 == d1[j] && oi1 < i1[j]);
      const float hi = take ? d1[j] : od1;
      d1[j] = take ? od1 : d1[j];
      i1[j] = take ? oi1 : i1[j];
      d2[j] = fminf(fminf(d2[j], od2), hi);
    }
  }

  // cross-wave (wc) merge via LDS (reuse Zl); zsq/dsum slices for loss reduce
  __syncthreads();
  float* rd1  = (float*)Zl;          // [0..256)
  int*   ri1  = (int*)Zl + 256;      // [256..512)
  float* rd2  = (float*)Zl + 512;    // [512..768)
  float* zsq  = (float*)Zl + 768;    // [768..1024)
  float* dsum = (float*)Zl + 1024;   // [1024..1152)
  if (lane < 16) {
    #pragma unroll
    for (int j = 0; j < 4; ++j) {
      const int p = wp * 64 + j * 16 + ln;
      rd1[wc * 128 + p] = d1[j];
      ri1[wc * 128 + p] = i1[j];
      rd2[wc * 128 + p] = d2[j];
    }
  }
  zsq[tid] = s_z2;
  __syncthreads();
  if (tid < 128) {
    const float a1 = rd1[tid], b1 = rd1[128 + tid];
    const int   ai = ri1[tid], bi = ri1[128 + tid];
    const float a2 = rd2[tid], b2 = rd2[128 + tid];
    const bool take = (b1 < a1) || (b1 == a1 && bi < ai);
    const float d1f = take ? b1 : a1;
    const int   i1f = take ? bi : ai;
    const float hi  = take ? a1 : b1;
    const float d2f = fminf(fminf(a2, b2), hi);
    const int gp = ptile + tid;
    idx_out[gp] = i1f;
    dsum[tid] = d1f;
    if ((d2f - d1f) <= TAU) {   // fp16 gap error sigma ~3e-2; TAU = 5 sigma
      const int pos = atomicAdd(ccount, 1);
      clist[pos] = gp;
    }
  }
  __syncthreads();
  // block loss partial: Σ_{px} d1 + Σ z²  -> one atomic per block
  if (tid < 64) {
    float v = zsq[tid] + zsq[tid + 64] + zsq[tid + 128] + zsq[tid + 192]
            + dsum[tid] + dsum[tid + 64];
    #pragma unroll
    for (int off = 32; off; off >>= 1) v += __shfl_down(v, off, 64);
    if (tid == 0) atomicAdd(acc_out, v);
  }
}

// K2: exact fp32 rescan. One block per group of 4 contested pixels, all 1024
// codewords in-block. fma chain per (cw,px) bit-identical to prior passing version.
__global__ __launch_bounds__(256)
void rescan_kernel(const float* __restrict__ z, const float* __restrict__ cb,
                   const float* __restrict__ e2, const int* __restrict__ clist,
                   const int* __restrict__ ccount, int* __restrict__ idx_out) {
  __shared__ __align__(16) float zl[4][C_DIM];    // [px][k] -> float4 broadcast reads
  __shared__ int pxs[4];
  __shared__ unsigned long long bestk[4];
  const int n = *ccount;
  const int ngroups = (n + 3) >> 2;
  for (int g = blockIdx.x; g < ngroups; g += gridDim.x) {
    const int base = g * 4;
    if ((int)threadIdx.x < 4) {
      pxs[threadIdx.x] = clist[min(base + (int)threadIdx.x, n - 1)];  // pad w/ dup (idempotent)
      bestk[threadIdx.x] = ~0ULL;
    }
    __syncthreads();
    {
      const int k = threadIdx.x;
      #pragma unroll
      for (int i = 0; i < 4; ++i) {
        const int gp = pxs[i];
        zl[i][k] = z[(size_t)(gp >> 12) * (C_DIM * HW) + (size_t)k * HW + (gp & 4095)];
      }
    }
    __syncthreads();
    unsigned long long mykey[4] = {~0ULL, ~0ULL, ~0ULL, ~0ULL};
    #pragma unroll 1
    for (int o = 0; o < 4; ++o) {
      const int cw = o * 256 + (int)threadIdx.x;
      const float* row = cb + (size_t)cw * C_DIM;
      float dot[4] = {0.f, 0.f, 0.f, 0.f};
      #pragma unroll 4
      for (int k0 = 0; k0 < C_DIM; k0 += 4) {
        const float4 ev = *(const float4*)(row + k0);   // coalesced-by-row, L2-hot
        #pragma unroll
        for (int i = 0; i < 4; ++i) {
          const float4 zz = *(const float4*)&zl[i][k0]; // uniform addr -> LDS broadcast
          dot[i] = fmaf(ev.x, zz.x, dot[i]);
          dot[i] = fmaf(ev.y, zz.y, dot[i]);
          dot[i] = fmaf(ev.z, zz.z, dot[i]);
          dot[i] = fmaf(ev.w, zz.w, dot[i]);
        }
      }
      const float ee = e2[cw];
      #pragma unroll
      for (int i = 0; i < 4; ++i) {
        const float d = fmaf(-2.0f, dot[i], ee);
        const unsigned long long key = ((unsigned long long)fenc(d) << 32) | (unsigned)cw;
        mykey[i] = key < mykey[i] ? key : mykey[i];
      }
    }
    // wave-level u64 min reduce, then 1 shared atomic per wave per pixel
    #pragma unroll
    for (int i = 0; i < 4; ++i) {
      unsigned long long k = mykey[i];
      #pragma unroll
      for (int off = 32; off; off >>= 1) {
        const unsigned long long ok = __shfl_xor(k, off, 64);
        k = ok < k ? ok : k;
      }
      if ((threadIdx.x & 63) == 0) atomicMin(&bestk[i], k);
    }
    __syncthreads();
    if ((int)threadIdx.x < 4)
      idx_out[pxs[threadIdx.x]] = (int)(unsigned)(bestk[threadIdx.x] & 0xFFFFFFFFull);
    __syncthreads();
  }
}

// K3: write-only scatter: out[b,:,p] = cb[idx[px]]. Loss no longer needs z here
// (folded into screen). cb rows are L2/L3-resident gathers; out writes are
// wave-coalesced (64 consecutive px, fixed channel). 64 px x 4 csegs per block.
__global__ __launch_bounds__(256)
void scatter_kernel(const float* __restrict__ cb, const int* __restrict__ idx,
                    float* __restrict__ out) {
  const int tid = threadIdx.x;
  const int px = blockIdx.x * 64 + (tid & 63);
  const int cbase = (tid >> 6) * 64;
  const int id = idx[px];
  const int b = px >> 12, p = px & 4095;
  float*       orow = out + (size_t)b * (C_DIM * HW) + p;
  const float* erow = cb + (size_t)id * C_DIM;
  #pragma unroll 4
  for (int c0 = cbase; c0 < cbase + 64; c0 += 4) {
    const float4 ev = *(const float4*)(erow + c0);
    orow[(size_t)(c0 + 0) * HW] = ev.x;
    orow[(size_t)(c0 + 1) * HW] = ev.y;
    orow[(size_t)(c0 + 2) * HW] = ev.z;
    orow[(size_t)(c0 + 3) * HW] = ev.w;
  }
}

__global__ void finalize_kernel(const float* __restrict__ acc, float* __restrict__ loss_out) {
  *loss_out = 1.25f * (*acc) * (1.0f / 16777216.0f);
}

extern "C" void kernel_launch(void* const* d_in, const int* in_sizes, int n_in,
                              void* d_out, int out_size, void* d_ws, size_t ws_size,
                              hipStream_t stream) {
  const float* z  = (const float*)d_in[0];
  const float* cb = (const float*)d_in[1];
  float* out = (float*)d_out;
  char* ws = (char*)d_ws;

  float*    acc    = (float*)ws;
  int*      ccount = (int*)(ws + 8);
  float*    e2     = (float*)(ws + 4096);
  _Float16* EhfP   = (_Float16*)(ws + 8192);
  int*      idx    = (int*)(ws + 532480);
  int*      clist  = (int*)(ws + 794624);

  (void)hipMemsetAsync(d_ws, 0, 16, stream);
  prep_kernel<<<384, 256, 0, stream>>>(cb, EhfP, e2);
  screen_kernel<<<NPIX / 128, 256, 0, stream>>>(z, EhfP, e2, idx, clist, ccount, acc);
  rescan_kernel<<<1024, 256, 0, stream>>>(z, cb, e2, clist, ccount, idx);
  scatter_kernel<<<NPIX / 64, 256, 0, stream>>>(cb, idx, out);
  finalize_kernel<<<1, 1, 0, stream>>>(acc, out + 16777216);
}

// Round 6
// 207.726 us; speedup vs baseline: 1.1506x; 1.0716x over previous
//
#include <hip/hip_runtime.h>
#include <cfloat>

#define C_DIM 256
#define HW    4096
#define NE    1024
#define NPIX  65536
#define TAU   0.15f
#define ZSTR  264   // fp16 per Z-LDS pixel row: 256 ch + 8 pad (528 B, 16B-aligned)

typedef __attribute__((ext_vector_type(8))) _Float16 half8_t;
typedef __attribute__((ext_vector_type(4))) float floatx4;

// monotone float -> uint32 (for packed (d,idx) u64 min with lowest-index tie-break)
__device__ __forceinline__ unsigned int fenc(float f) {
  unsigned int u = __float_as_uint(f);
  return (u & 0x80000000u) ? ~u : (u | 0x80000000u);
}

// ---------------- ws layout ----------------
// @0       float acc (Σ d1 + Σ z², loss numerator)  [zeroed per launch]
// @8       int   ccount                             [zeroed per launch]
// @4096    float e2[1024]
// @8192    _Float16 EhfP[1024*256]     (512 KiB fp16 codebook, MFMA-fragment-packed)
// @532480  int   clist[65536]          (256 KiB, ends 794624)

// K0 (fused): blocks [0,128) pack codebook into MFMA A-fragment order;
// blocks [128,384) compute ||e||^2 per codeword (one wave per codeword).
__global__ __launch_bounds__(256)
void prep_kernel(const float* __restrict__ cb, _Float16* __restrict__ EhfP,
                 float* __restrict__ e2) {
  if (blockIdx.x < 128) {
    const int g = blockIdx.x >> 3, it = blockIdx.x & 7;
    const int sidx = it * 256 + (int)threadIdx.x;       // (ks*256 + i*64 + lane)
    const int ks = sidx >> 8, i = (sidx >> 6) & 3, lane = sidx & 63;
    const int ln = lane & 15, quad = lane >> 4;
    const float* src = cb + (size_t)(g * 64 + i * 16 + ln) * C_DIM + ks * 32 + quad * 8;
    const float4 v0 = *(const float4*)(src);
    const float4 v1 = *(const float4*)(src + 4);
    half8_t h;
    h[0] = (_Float16)v0.x; h[1] = (_Float16)v0.y; h[2] = (_Float16)v0.z; h[3] = (_Float16)v0.w;
    h[4] = (_Float16)v1.x; h[5] = (_Float16)v1.y; h[6] = (_Float16)v1.z; h[7] = (_Float16)v1.w;
    *(half8_t*)(EhfP + (size_t)g * 16384 + (size_t)sidx * 8) = h;
  } else {
    const int bid = blockIdx.x - 128;
    const int wave = (bid * 256 + (int)threadIdx.x) >> 6;
    const int lane = threadIdx.x & 63;
    const float4 v = *(const float4*)(cb + (size_t)wave * C_DIM + lane * 4);
    float s = v.x * v.x + v.y * v.y + v.z * v.z + v.w * v.w;
    #pragma unroll
    for (int off = 32; off; off >>= 1) s += __shfl_down(s, off, 64);
    if (lane == 0) e2[wave] = s;
  }
}

// K1: fp16 MFMA screen (proven 128-px/j=4 structure) + fused loss accumulation
// + FUSED OUTPUT WRITE: out[b,:,p] = cb[winner] for all 128 px (provisional for
// contested px; rescan overwrites those). The idx array and the standalone
// scatter kernel are eliminated — the cb-gather/strided-write now overlaps with
// co-resident blocks' MFMA work instead of running as a latency-bound kernel.
__global__ __launch_bounds__(256, 2)
void screen_kernel(const float* __restrict__ z, const _Float16* __restrict__ EhfP,
                   const float* __restrict__ e2, const float* __restrict__ cb,
                   int* __restrict__ clist, int* __restrict__ ccount,
                   float* __restrict__ acc_out, float* __restrict__ out) {
  __shared__ __align__(16) _Float16 Zl[128 * ZSTR];   // 67584 B
  __shared__ float e2l[NE];                           // 4096 B

  const int tid = threadIdx.x;
  const int ptile = blockIdx.x * 128;
  const int b = ptile >> 12, pb = ptile & 4095;
  const float* zb = z + (size_t)b * (C_DIM * HW) + pb;

  // stage Z: z[k][p] fp32 -> Zl[p][k] fp16; accumulate Σz² in fp32 on the side.
  float s_z2 = 0.f;
  #pragma unroll
  for (int it = 0; it < 16; ++it) {
    const int flat = it * 256 + tid;
    const int p = flat & 127, kb = flat >> 7;
    float f[8];
    #pragma unroll
    for (int j = 0; j < 8; ++j) f[j] = zb[(size_t)(kb * 8 + j) * HW + p];
    half8_t h;
    #pragma unroll
    for (int j = 0; j < 8; ++j) { s_z2 = fmaf(f[j], f[j], s_z2); h[j] = (_Float16)f[j]; }
    *(half8_t*)&Zl[p * ZSTR + kb * 8] = h;
  }
  #pragma unroll
  for (int i = 0; i < 4; ++i) e2l[i * 256 + tid] = e2[i * 256 + tid];
  __syncthreads();

  const int lane = tid & 63;
  const int w = tid >> 6;
  const int wc = w & 1, wp = w >> 1;
  const int ln = lane & 15, quad = lane >> 4;

  // A stream: wave wc's fragments for chunk nc at EhfP + (nc*2+wc)*16384 halves;
  // step (nc,ks), frag i: + ks*2048 + i*512 + lane*8 halves (16B/lane, coalesced).
  const _Float16* aBase = EhfP + (size_t)wc * 16384 + (size_t)lane * 8;
  const char* rowB[4];
  #pragma unroll
  for (int j = 0; j < 4; ++j)
    rowB[j] = (const char*)(&Zl[(wp * 64 + j * 16 + ln) * ZSTR + quad * 8]);

  float d1[4], d2[4]; int i1[4];
  #pragma unroll
  for (int j = 0; j < 4; ++j) { d1[j] = FLT_MAX; d2[j] = FLT_MAX; i1[j] = 0; }

  half8_t abuf[2][4], bbuf[2][4];
  // prologue: fragments for step 0 (nc=0, ks=0)
  #pragma unroll
  for (int i = 0; i < 4; ++i) abuf[0][i] = *(const half8_t*)(aBase + i * 512);
  #pragma unroll
  for (int j = 0; j < 4; ++j) bbuf[0][j] = *(const half8_t*)(rowB[j]);

  for (int nc = 0; nc < 8; ++nc) {
    floatx4 acc[4][4];
    #pragma unroll
    for (int i = 0; i < 4; ++i)
      #pragma unroll
      for (int j = 0; j < 4; ++j) acc[i][j] = (floatx4){0.f, 0.f, 0.f, 0.f};

    #pragma unroll
    for (int ks = 0; ks < 8; ++ks) {
      const int cur = ks & 1, nxt = cur ^ 1;
      // prefetch step s+1 (clamped to last step: redundant reload, in-bounds)
      const int s1 = nc * 8 + ks + 1;
      const int sp = s1 > 63 ? 63 : s1;
      const size_t aoff = (size_t)(sp >> 3) * 32768 + (size_t)(sp & 7) * 2048;
      const int bks = sp & 7;
      #pragma unroll
      for (int i = 0; i < 4; ++i) abuf[nxt][i] = *(const half8_t*)(aBase + aoff + i * 512);
      #pragma unroll
      for (int j = 0; j < 4; ++j) bbuf[nxt][j] = *(const half8_t*)(rowB[j] + bks * 64);
      // compute on current buffers
      #pragma unroll
      for (int i = 0; i < 4; ++i)
        #pragma unroll
        for (int j = 0; j < 4; ++j)
          acc[i][j] = __builtin_amdgcn_mfma_f32_16x16x32_f16(abuf[cur][i], bbuf[cur][j], acc[i][j], 0, 0, 0);
    }

    // epilogue: d' = e2 - 2*dot; per-lane (d1,i1,d2). cw index ascending -> '<' keeps first.
    const int cwb = nc * 128 + wc * 64;
    #pragma unroll
    for (int i = 0; i < 4; ++i) {
      const int cw0 = cwb + i * 16 + quad * 4;    // C/D: row = quad*4 + r (codeword)
      float ee[4];
      #pragma unroll
      for (int r = 0; r < 4; ++r) ee[r] = e2l[cw0 + r];
      #pragma unroll
      for (int j = 0; j < 4; ++j) {
        #pragma unroll
        for (int r = 0; r < 4; ++r) {
          const float d = fmaf(-2.0f, acc[i][j][r], ee[r]);
          const bool lt = d < d1[j];
          const float hi = lt ? d1[j] : d;
          d1[j] = lt ? d : d1[j];
          i1[j] = lt ? (cw0 + r) : i1[j];
          d2[j] = fminf(d2[j], hi);
        }
      }
    }
  }

  // cross-quad butterfly (lanes l, l^16, l^32 share pixel col = lane&15)
  #pragma unroll
  for (int j = 0; j < 4; ++j) {
    #pragma unroll
    for (int m = 16; m <= 32; m <<= 1) {
      const float od1 = __shfl_xor(d1[j], m, 64);
      const int   oi1 = __shfl_xor(i1[j], m, 64);
      const float od2 = __shfl_xor(d2[j], m, 64);
      const bool take = (od1 < d1[j]) || (od1 == d1[j] && oi1 < i1[j]);
      const float hi = take ? d1[j] : od1;
      d1[j] = take ? od1 : d1[j];
      i1[j] = take ? oi1 : i1[j];
      d2[j] = fminf(fminf(d2[j], od2), hi);
    }
  }

  // cross-wave (wc) merge via LDS (reuse Zl); zsq/dsum/fid slices for loss + out-write
  __syncthreads();
  float* rd1  = (float*)Zl;          // [0..256)
  int*   ri1  = (int*)Zl + 256;      // [256..512)
  float* rd2  = (float*)Zl + 512;    // [512..768)
  float* zsq  = (float*)Zl + 768;    // [768..1024)
  float* dsum = (float*)Zl + 1024;   // [1024..1152)
  int*   fid  = (int*)Zl + 1152;     // [1152..1280)
  if (lane < 16) {
    #pragma unroll
    for (int j = 0; j < 4; ++j) {
      const int p = wp * 64 + j * 16 + ln;
      rd1[wc * 128 + p] = d1[j];
      ri1[wc * 128 + p] = i1[j];
      rd2[wc * 128 + p] = d2[j];
    }
  }
  zsq[tid] = s_z2;
  __syncthreads();
  if (tid < 128) {
    const float a1 = rd1[tid], b1 = rd1[128 + tid];
    const int   ai = ri1[tid], bi = ri1[128 + tid];
    const float a2 = rd2[tid], b2 = rd2[128 + tid];
    const bool take = (b1 < a1) || (b1 == a1 && bi < ai);
    const float d1f = take ? b1 : a1;
    const int   i1f = take ? bi : ai;
    const float hi  = take ? a1 : b1;
    const float d2f = fminf(fminf(a2, b2), hi);
    fid[tid]  = i1f;
    dsum[tid] = d1f;
    if ((d2f - d1f) <= TAU) {   // fp16 gap error sigma ~3e-2; TAU = 5 sigma
      const int pos = atomicAdd(ccount, 1);
      clist[pos] = ptile + tid;
    }
  }
  __syncthreads();
  // block loss partial: Σ_{px} d1 + Σ z²  -> one atomic per block
  if (tid < 64) {
    float v = zsq[tid] + zsq[tid + 64] + zsq[tid + 128] + zsq[tid + 192]
            + dsum[tid] + dsum[tid + 64];
    #pragma unroll
    for (int off = 32; off; off >>= 1) v += __shfl_down(v, off, 64);
    if (tid == 0) atomicAdd(acc_out, v);
  }
  // fused output write: thread t -> pixel (t&127), channel half (t>>7)*128.
  // Wave lanes = 64 consecutive px at fixed channel -> coalesced 256B stores;
  // cb rows gathered from L2 (1 MB resident).
  {
    const int pl = tid & 127, cs = tid >> 7;
    const int id = fid[pl];
    const float* er = cb + (size_t)id * C_DIM + cs * 128;
    float* orow = out + (size_t)b * (C_DIM * HW) + (size_t)(cs * 128) * HW + pb + pl;
    #pragma unroll 8
    for (int c = 0; c < 128; c += 4) {
      const float4 ev = *(const float4*)(er + c);
      orow[(size_t)(c + 0) * HW] = ev.x;
      orow[(size_t)(c + 1) * HW] = ev.y;
      orow[(size_t)(c + 2) * HW] = ev.z;
      orow[(size_t)(c + 3) * HW] = ev.w;
    }
  }
}

// K2: exact fp32 rescan. One block per group of 4 contested pixels, all 1024
// codewords in-block. fma chain per (cw,px) bit-identical to prior passing
// version. After the argmin, each wave REWRITES the out row for its pixel
// (overwriting screen's provisional write).
__global__ __launch_bounds__(256)
void rescan_kernel(const float* __restrict__ z, const float* __restrict__ cb,
                   const float* __restrict__ e2, const int* __restrict__ clist,
                   const int* __restrict__ ccount, float* __restrict__ out) {
  __shared__ __align__(16) float zl[4][C_DIM];    // [px][k] -> float4 broadcast reads
  __shared__ int pxs[4];
  __shared__ unsigned long long bestk[4];
  const int n = *ccount;
  const int ngroups = (n + 3) >> 2;
  for (int g = blockIdx.x; g < ngroups; g += gridDim.x) {
    const int base = g * 4;
    if ((int)threadIdx.x < 4) {
      pxs[threadIdx.x] = clist[min(base + (int)threadIdx.x, n - 1)];  // pad w/ dup (idempotent)
      bestk[threadIdx.x] = ~0ULL;
    }
    __syncthreads();
    {
      const int k = threadIdx.x;
      #pragma unroll
      for (int i = 0; i < 4; ++i) {
        const int gp = pxs[i];
        zl[i][k] = z[(size_t)(gp >> 12) * (C_DIM * HW) + (size_t)k * HW + (gp & 4095)];
      }
    }
    __syncthreads();
    unsigned long long mykey[4] = {~0ULL, ~0ULL, ~0ULL, ~0ULL};
    #pragma unroll 1
    for (int o = 0; o < 4; ++o) {
      const int cw = o * 256 + (int)threadIdx.x;
      const float* row = cb + (size_t)cw * C_DIM;
      float dot[4] = {0.f, 0.f, 0.f, 0.f};
      #pragma unroll 4
      for (int k0 = 0; k0 < C_DIM; k0 += 4) {
        const float4 ev = *(const float4*)(row + k0);   // coalesced-by-row, L2-hot
        #pragma unroll
        for (int i = 0; i < 4; ++i) {
          const float4 zz = *(const float4*)&zl[i][k0]; // uniform addr -> LDS broadcast
          dot[i] = fmaf(ev.x, zz.x, dot[i]);
          dot[i] = fmaf(ev.y, zz.y, dot[i]);
          dot[i] = fmaf(ev.z, zz.z, dot[i]);
          dot[i] = fmaf(ev.w, zz.w, dot[i]);
        }
      }
      const float ee = e2[cw];
      #pragma unroll
      for (int i = 0; i < 4; ++i) {
        const float d = fmaf(-2.0f, dot[i], ee);
        const unsigned long long key = ((unsigned long long)fenc(d) << 32) | (unsigned)cw;
        mykey[i] = key < mykey[i] ? key : mykey[i];
      }
    }
    // wave-level u64 min reduce, then 1 shared atomic per wave per pixel
    #pragma unroll
    for (int i = 0; i < 4; ++i) {
      unsigned long long k = mykey[i];
      #pragma unroll
      for (int off = 32; off; off >>= 1) {
        const unsigned long long ok = __shfl_xor(k, off, 64);
        k = ok < k ? ok : k;
      }
      if ((threadIdx.x & 63) == 0) atomicMin(&bestk[i], k);
    }
    __syncthreads();
    // rewrite out row for this wave's pixel (duplicate-padded px: identical writes)
    {
      const int i = (int)threadIdx.x >> 6;
      const int l = (int)threadIdx.x & 63;
      const int gp = pxs[i];
      const int id = (int)(unsigned)(bestk[i] & 0xFFFFFFFFull);
      const float* er = cb + (size_t)id * C_DIM;
      float* orow = out + (size_t)(gp >> 12) * (C_DIM * HW) + (gp & 4095);
      const float4 ev = *(const float4*)(er + l * 4);   // coalesced row read
      orow[(size_t)(l * 4 + 0) * HW] = ev.x;
      orow[(size_t)(l * 4 + 1) * HW] = ev.y;
      orow[(size_t)(l * 4 + 2) * HW] = ev.z;
      orow[(size_t)(l * 4 + 3) * HW] = ev.w;
    }
    __syncthreads();
  }
}

__global__ void finalize_kernel(const float* __restrict__ acc, float* __restrict__ loss_out) {
  *loss_out = 1.25f * (*acc) * (1.0f / 16777216.0f);
}

extern "C" void kernel_launch(void* const* d_in, const int* in_sizes, int n_in,
                              void* d_out, int out_size, void* d_ws, size_t ws_size,
                              hipStream_t stream) {
  const float* z  = (const float*)d_in[0];
  const float* cb = (const float*)d_in[1];
  float* out = (float*)d_out;
  char* ws = (char*)d_ws;

  float*    acc    = (float*)ws;
  int*      ccount = (int*)(ws + 8);
  float*    e2     = (float*)(ws + 4096);
  _Float16* EhfP   = (_Float16*)(ws + 8192);
  int*      clist  = (int*)(ws + 532480);

  (void)hipMemsetAsync(d_ws, 0, 16, stream);
  prep_kernel<<<384, 256, 0, stream>>>(cb, EhfP, e2);
  screen_kernel<<<NPIX / 128, 256, 0, stream>>>(z, EhfP, e2, cb, clist, ccount, acc, out);
  rescan_kernel<<<1024, 256, 0, stream>>>(z, cb, e2, clist, ccount, out);
  finalize_kernel<<<1, 1, 0, stream>>>(acc, out + 16777216);
}

// Round 7
// 193.117 us; speedup vs baseline: 1.2377x; 1.0756x over previous
//
#include <hip/hip_runtime.h>
#include <cfloat>

#define C_DIM 256
#define HW    4096
#define NE    1024
#define NPIX  65536
#define TAU   0.15f
#define ZSTR  264   // fp16 per Z-LDS pixel row: 256 ch + 8 pad (528 B, 16B-aligned)

typedef __attribute__((ext_vector_type(8))) _Float16 half8_t;
typedef __attribute__((ext_vector_type(4))) float floatx4;

// monotone float -> uint32 (for packed (d,idx) u64 min with lowest-index tie-break)
__device__ __forceinline__ unsigned int fenc(float f) {
  unsigned int u = __float_as_uint(f);
  return (u & 0x80000000u) ? ~u : (u | 0x80000000u);
}

// ---------------- ws layout ----------------
// @0       float acc (Σ d1 + Σ z², loss numerator)  [zeroed by prep]
// @8       int   ccount                             [zeroed by prep]
// @4096    float e2[1024]
// @8192    _Float16 EhfP[1024*256]     (512 KiB fp16 codebook, MFMA-fragment-packed)
// @532480  int   clist[65536]          (256 KiB, ends 794624)

// K0 (fused): blocks [0,128) pack codebook into MFMA A-fragment order;
// blocks [128,384) compute ||e||^2 per codeword (one wave per codeword).
// Block 128 additionally zeroes acc/ccount (prep precedes screen in stream
// order, so this replaces the hipMemsetAsync launch).
__global__ __launch_bounds__(256)
void prep_kernel(const float* __restrict__ cb, _Float16* __restrict__ EhfP,
                 float* __restrict__ e2, float* __restrict__ acc,
                 int* __restrict__ ccount) {
  if (blockIdx.x < 128) {
    const int g = blockIdx.x >> 3, it = blockIdx.x & 7;
    const int sidx = it * 256 + (int)threadIdx.x;       // (ks*256 + i*64 + lane)
    const int ks = sidx >> 8, i = (sidx >> 6) & 3, lane = sidx & 63;
    const int ln = lane & 15, quad = lane >> 4;
    const float* src = cb + (size_t)(g * 64 + i * 16 + ln) * C_DIM + ks * 32 + quad * 8;
    const float4 v0 = *(const float4*)(src);
    const float4 v1 = *(const float4*)(src + 4);
    half8_t h;
    h[0] = (_Float16)v0.x; h[1] = (_Float16)v0.y; h[2] = (_Float16)v0.z; h[3] = (_Float16)v0.w;
    h[4] = (_Float16)v1.x; h[5] = (_Float16)v1.y; h[6] = (_Float16)v1.z; h[7] = (_Float16)v1.w;
    *(half8_t*)(EhfP + (size_t)g * 16384 + (size_t)sidx * 8) = h;
  } else {
    if (blockIdx.x == 128 && threadIdx.x == 0) { acc[0] = 0.f; ccount[0] = 0; }
    const int bid = blockIdx.x - 128;
    const int wave = (bid * 256 + (int)threadIdx.x) >> 6;
    const int lane = threadIdx.x & 63;
    const float4 v = *(const float4*)(cb + (size_t)wave * C_DIM + lane * 4);
    float s = v.x * v.x + v.y * v.y + v.z * v.z + v.w * v.w;
    #pragma unroll
    for (int off = 32; off; off >>= 1) s += __shfl_down(s, off, 64);
    if (lane == 0) e2[wave] = s;
  }
}

// K1: fp16 MFMA screen (proven 128-px/j=4 structure) + fused loss accumulation
// + fused output write (provisional for contested px; rescan overwrites).
// NEW: s_setprio(1) around the MFMA cluster — waves/blocks on a CU are in
// different phases (stage/K-loop/write, no intra-loop barriers), so priority
// keeps the matrix pipe fed while other waves issue memory ops.
__global__ __launch_bounds__(256, 2)
void screen_kernel(const float* __restrict__ z, const _Float16* __restrict__ EhfP,
                   const float* __restrict__ e2, const float* __restrict__ cb,
                   int* __restrict__ clist, int* __restrict__ ccount,
                   float* __restrict__ acc_out, float* __restrict__ out) {
  __shared__ __align__(16) _Float16 Zl[128 * ZSTR];   // 67584 B
  __shared__ float e2l[NE];                           // 4096 B

  const int tid = threadIdx.x;
  const int ptile = blockIdx.x * 128;
  const int b = ptile >> 12, pb = ptile & 4095;
  const float* zb = z + (size_t)b * (C_DIM * HW) + pb;

  // stage Z: z[k][p] fp32 -> Zl[p][k] fp16; accumulate Σz² in fp32 on the side.
  float s_z2 = 0.f;
  #pragma unroll
  for (int it = 0; it < 16; ++it) {
    const int flat = it * 256 + tid;
    const int p = flat & 127, kb = flat >> 7;
    float f[8];
    #pragma unroll
    for (int j = 0; j < 8; ++j) f[j] = zb[(size_t)(kb * 8 + j) * HW + p];
    half8_t h;
    #pragma unroll
    for (int j = 0; j < 8; ++j) { s_z2 = fmaf(f[j], f[j], s_z2); h[j] = (_Float16)f[j]; }
    *(half8_t*)&Zl[p * ZSTR + kb * 8] = h;
  }
  #pragma unroll
  for (int i = 0; i < 4; ++i) e2l[i * 256 + tid] = e2[i * 256 + tid];
  __syncthreads();

  const int lane = tid & 63;
  const int w = tid >> 6;
  const int wc = w & 1, wp = w >> 1;
  const int ln = lane & 15, quad = lane >> 4;

  // A stream: wave wc's fragments for chunk nc at EhfP + (nc*2+wc)*16384 halves;
  // step (nc,ks), frag i: + ks*2048 + i*512 + lane*8 halves (16B/lane, coalesced).
  const _Float16* aBase = EhfP + (size_t)wc * 16384 + (size_t)lane * 8;
  const char* rowB[4];
  #pragma unroll
  for (int j = 0; j < 4; ++j)
    rowB[j] = (const char*)(&Zl[(wp * 64 + j * 16 + ln) * ZSTR + quad * 8]);

  float d1[4], d2[4]; int i1[4];
  #pragma unroll
  for (int j = 0; j < 4; ++j) { d1[j] = FLT_MAX; d2[j] = FLT_MAX; i1[j] = 0; }

  half8_t abuf[2][4], bbuf[2][4];
  // prologue: fragments for step 0 (nc=0, ks=0)
  #pragma unroll
  for (int i = 0; i < 4; ++i) abuf[0][i] = *(const half8_t*)(aBase + i * 512);
  #pragma unroll
  for (int j = 0; j < 4; ++j) bbuf[0][j] = *(const half8_t*)(rowB[j]);

  for (int nc = 0; nc < 8; ++nc) {
    floatx4 acc[4][4];
    #pragma unroll
    for (int i = 0; i < 4; ++i)
      #pragma unroll
      for (int j = 0; j < 4; ++j) acc[i][j] = (floatx4){0.f, 0.f, 0.f, 0.f};

    #pragma unroll
    for (int ks = 0; ks < 8; ++ks) {
      const int cur = ks & 1, nxt = cur ^ 1;
      // prefetch step s+1 (clamped to last step: redundant reload, in-bounds)
      const int s1 = nc * 8 + ks + 1;
      const int sp = s1 > 63 ? 63 : s1;
      const size_t aoff = (size_t)(sp >> 3) * 32768 + (size_t)(sp & 7) * 2048;
      const int bks = sp & 7;
      #pragma unroll
      for (int i = 0; i < 4; ++i) abuf[nxt][i] = *(const half8_t*)(aBase + aoff + i * 512);
      #pragma unroll
      for (int j = 0; j < 4; ++j) bbuf[nxt][j] = *(const half8_t*)(rowB[j] + bks * 64);
      // compute on current buffers (priority-boosted)
      __builtin_amdgcn_s_setprio(1);
      #pragma unroll
      for (int i = 0; i < 4; ++i)
        #pragma unroll
        for (int j = 0; j < 4; ++j)
          acc[i][j] = __builtin_amdgcn_mfma_f32_16x16x32_f16(abuf[cur][i], bbuf[cur][j], acc[i][j], 0, 0, 0);
      __builtin_amdgcn_s_setprio(0);
    }

    // epilogue: d' = e2 - 2*dot; per-lane (d1,i1,d2). cw index ascending -> '<' keeps first.
    const int cwb = nc * 128 + wc * 64;
    #pragma unroll
    for (int i = 0; i < 4; ++i) {
      const int cw0 = cwb + i * 16 + quad * 4;    // C/D: row = quad*4 + r (codeword)
      float ee[4];
      #pragma unroll
      for (int r = 0; r < 4; ++r) ee[r] = e2l[cw0 + r];
      #pragma unroll
      for (int j = 0; j < 4; ++j) {
        #pragma unroll
        for (int r = 0; r < 4; ++r) {
          const float d = fmaf(-2.0f, acc[i][j][r], ee[r]);
          const bool lt = d < d1[j];
          const float hi = lt ? d1[j] : d;
          d1[j] = lt ? d : d1[j];
          i1[j] = lt ? (cw0 + r) : i1[j];
          d2[j] = fminf(d2[j], hi);
        }
      }
    }
  }

  // cross-quad butterfly (lanes l, l^16, l^32 share pixel col = lane&15)
  #pragma unroll
  for (int j = 0; j < 4; ++j) {
    #pragma unroll
    for (int m = 16; m <= 32; m <<= 1) {
      const float od1 = __shfl_xor(d1[j], m, 64);
      const int   oi1 = __shfl_xor(i1[j], m, 64);
      const float od2 = __shfl_xor(d2[j], m, 64);
      const bool take = (od1 < d1[j]) || (od1 == d1[j] && oi1 < i1[j]);
      const float hi = take ? d1[j] : od1;
      d1[j] = take ? od1 : d1[j];
      i1[j] = take ? oi1 : i1[j];
      d2[j] = fminf(fminf(d2[j], od2), hi);
    }
  }

  // cross-wave (wc) merge via LDS (reuse Zl); zsq/dsum/fid slices for loss + out-write
  __syncthreads();
  float* rd1  = (float*)Zl;          // [0..256)
  int*   ri1  = (int*)Zl + 256;      // [256..512)
  float* rd2  = (float*)Zl + 512;    // [512..768)
  float* zsq  = (float*)Zl + 768;    // [768..1024)
  float* dsum = (float*)Zl + 1024;   // [1024..1152)
  int*   fid  = (int*)Zl + 1152;     // [1152..1280)
  if (lane < 16) {
    #pragma unroll
    for (int j = 0; j < 4; ++j) {
      const int p = wp * 64 + j * 16 + ln;
      rd1[wc * 128 + p] = d1[j];
      ri1[wc * 128 + p] = i1[j];
      rd2[wc * 128 + p] = d2[j];
    }
  }
  zsq[tid] = s_z2;
  __syncthreads();
  if (tid < 128) {
    const float a1 = rd1[tid], b1 = rd1[128 + tid];
    const int   ai = ri1[tid], bi = ri1[128 + tid];
    const float a2 = rd2[tid], b2 = rd2[128 + tid];
    const bool take = (b1 < a1) || (b1 == a1 && bi < ai);
    const float d1f = take ? b1 : a1;
    const int   i1f = take ? bi : ai;
    const float hi  = take ? a1 : b1;
    const float d2f = fminf(fminf(a2, b2), hi);
    fid[tid]  = i1f;
    dsum[tid] = d1f;
    if ((d2f - d1f) <= TAU) {   // fp16 gap error sigma ~3e-2; TAU = 5 sigma
      const int pos = atomicAdd(ccount, 1);
      clist[pos] = ptile + tid;
    }
  }
  __syncthreads();
  // block loss partial: Σ_{px} d1 + Σ z²  -> one atomic per block
  if (tid < 64) {
    float v = zsq[tid] + zsq[tid + 64] + zsq[tid + 128] + zsq[tid + 192]
            + dsum[tid] + dsum[tid + 64];
    #pragma unroll
    for (int off = 32; off; off >>= 1) v += __shfl_down(v, off, 64);
    if (tid == 0) atomicAdd(acc_out, v);
  }
  // fused output write: thread t -> pixel (t&127), channel half (t>>7)*128.
  // Wave lanes = 64 consecutive px at fixed channel -> coalesced 256B stores;
  // cb rows gathered from L2 (1 MB resident).
  {
    const int pl = tid & 127, cs = tid >> 7;
    const int id = fid[pl];
    const float* er = cb + (size_t)id * C_DIM + cs * 128;
    float* orow = out + (size_t)b * (C_DIM * HW) + (size_t)(cs * 128) * HW + pb + pl;
    #pragma unroll 8
    for (int c = 0; c < 128; c += 4) {
      const float4 ev = *(const float4*)(er + c);
      orow[(size_t)(c + 0) * HW] = ev.x;
      orow[(size_t)(c + 1) * HW] = ev.y;
      orow[(size_t)(c + 2) * HW] = ev.z;
      orow[(size_t)(c + 3) * HW] = ev.w;
    }
  }
}

// K2: exact fp32 rescan. One block per group of 4 contested pixels, all 1024
// codewords in-block. fma chain per (cw,px) bit-identical to prior passing
// version. After the argmin, each wave rewrites the out row for its pixel.
// Block 0 also writes the final loss at START: acc is complete because screen
// finished before rescan began (stream order) — no extra sync needed. This
// replaces the finalize_kernel launch.
__global__ __launch_bounds__(256)
void rescan_kernel(const float* __restrict__ z, const float* __restrict__ cb,
                   const float* __restrict__ e2, const int* __restrict__ clist,
                   const int* __restrict__ ccount, float* __restrict__ out,
                   const float* __restrict__ acc, float* __restrict__ loss_out) {
  if (blockIdx.x == 0 && threadIdx.x == 0)
    *loss_out = 1.25f * (*acc) * (1.0f / 16777216.0f);
  __shared__ __align__(16) float zl[4][C_DIM];    // [px][k] -> float4 broadcast reads
  __shared__ int pxs[4];
  __shared__ unsigned long long bestk[4];
  const int n = *ccount;
  const int ngroups = (n + 3) >> 2;
  for (int g = blockIdx.x; g < ngroups; g += gridDim.x) {
    const int base = g * 4;
    if ((int)threadIdx.x < 4) {
      pxs[threadIdx.x] = clist[min(base + (int)threadIdx.x, n - 1)];  // pad w/ dup (idempotent)
      bestk[threadIdx.x] = ~0ULL;
    }
    __syncthreads();
    {
      const int k = threadIdx.x;
      #pragma unroll
      for (int i = 0; i < 4; ++i) {
        const int gp = pxs[i];
        zl[i][k] = z[(size_t)(gp >> 12) * (C_DIM * HW) + (size_t)k * HW + (gp & 4095)];
      }
    }
    __syncthreads();
    unsigned long long mykey[4] = {~0ULL, ~0ULL, ~0ULL, ~0ULL};
    #pragma unroll 1
    for (int o = 0; o < 4; ++o) {
      const int cw = o * 256 + (int)threadIdx.x;
      const float* row = cb + (size_t)cw * C_DIM;
      float dot[4] = {0.f, 0.f, 0.f, 0.f};
      #pragma unroll 4
      for (int k0 = 0; k0 < C_DIM; k0 += 4) {
        const float4 ev = *(const float4*)(row + k0);   // coalesced-by-row, L2-hot
        #pragma unroll
        for (int i = 0; i < 4; ++i) {
          const float4 zz = *(const float4*)&zl[i][k0]; // uniform addr -> LDS broadcast
          dot[i] = fmaf(ev.x, zz.x, dot[i]);
          dot[i] = fmaf(ev.y, zz.y, dot[i]);
          dot[i] = fmaf(ev.z, zz.z, dot[i]);
          dot[i] = fmaf(ev.w, zz.w, dot[i]);
        }
      }
      const float ee = e2[cw];
      #pragma unroll
      for (int i = 0; i < 4; ++i) {
        const float d = fmaf(-2.0f, dot[i], ee);
        const unsigned long long key = ((unsigned long long)fenc(d) << 32) | (unsigned)cw;
        mykey[i] = key < mykey[i] ? key : mykey[i];
      }
    }
    // wave-level u64 min reduce, then 1 shared atomic per wave per pixel
    #pragma unroll
    for (int i = 0; i < 4; ++i) {
      unsigned long long k = mykey[i];
      #pragma unroll
      for (int off = 32; off; off >>= 1) {
        const unsigned long long ok = __shfl_xor(k, off, 64);
        k = ok < k ? ok : k;
      }
      if ((threadIdx.x & 63) == 0) atomicMin(&bestk[i], k);
    }
    __syncthreads();
    // rewrite out row for this wave's pixel (duplicate-padded px: identical writes)
    {
      const int i = (int)threadIdx.x >> 6;
      const int l = (int)threadIdx.x & 63;
      const int gp = pxs[i];
      const int id = (int)(unsigned)(bestk[i] & 0xFFFFFFFFull);
      const float* er = cb + (size_t)id * C_DIM;
      float* orow = out + (size_t)(gp >> 12) * (C_DIM * HW) + (gp & 4095);
      const float4 ev = *(const float4*)(er + l * 4);   // coalesced row read
      orow[(size_t)(l * 4 + 0) * HW] = ev.x;
      orow[(size_t)(l * 4 + 1) * HW] = ev.y;
      orow[(size_t)(l * 4 + 2) * HW] = ev.z;
      orow[(size_t)(l * 4 + 3) * HW] = ev.w;
    }
    __syncthreads();
  }
}

extern "C" void kernel_launch(void* const* d_in, const int* in_sizes, int n_in,
                              void* d_out, int out_size, void* d_ws, size_t ws_size,
                              hipStream_t stream) {
  const float* z  = (const float*)d_in[0];
  const float* cb = (const float*)d_in[1];
  float* out = (float*)d_out;
  char* ws = (char*)d_ws;

  float*    acc    = (float*)ws;
  int*      ccount = (int*)(ws + 8);
  float*    e2     = (float*)(ws + 4096);
  _Float16* EhfP   = (_Float16*)(ws + 8192);
  int*      clist  = (int*)(ws + 532480);

  prep_kernel<<<384, 256, 0, stream>>>(cb, EhfP, e2, acc, ccount);
  screen_kernel<<<NPIX / 128, 256, 0, stream>>>(z, EhfP, e2, cb, clist, ccount, acc, out);
  rescan_kernel<<<1024, 256, 0, stream>>>(z, cb, e2, clist, ccount, out, acc,
                                          out + 16777216);
}